// Round 7
// baseline (281.379 us; speedup 1.0000x reference)
//
#include <hip/hip_runtime.h>
#include <hip/hip_bf16.h>

typedef __attribute__((ext_vector_type(8))) short short8;
typedef __attribute__((ext_vector_type(16))) float f32x16;
typedef __attribute__((ext_vector_type(4))) float f32x4;

static constexpr int NN = 64;
static constexpr int C  = 128;
static constexpr int H  = 56;
static constexpr int W  = 56;
static constexpr int HP = 58;          // padded spatial extent
static constexpr int ROWB = HP * 256;  // padded row stride in bytes (NHWC bf16)
static constexpr int XSLOT = 15360;    // LDS bytes per X row slot (15 x 1KB)

__device__ __forceinline__ void gload16(const void* g, void* l) {
    __builtin_amdgcn_global_load_lds(
        (const __attribute__((address_space(1))) unsigned int*)g,
        (__attribute__((address_space(3))) unsigned int*)l, 16, 0, 0);
}

__device__ __forceinline__ f32x16 mfma32(short8 a, short8 b, f32x16 c) {
    return __builtin_amdgcn_mfma_f32_32x32x16_bf16(a, b, c, 0, 0, 0);
}

// ---------------------------------------------------------------------------
// Pack weights into MFMA-fragment order (verified in rounds 3-5):
//   Wp2[((tap*8 + ks)*2 + hi)*128 + o][j]  (bf16, j=0..7), c = ks*16+hi*8+j
// Each half-tap (4 ks values) is a contiguous 16 KB B-tile.
// ---------------------------------------------------------------------------
__global__ __launch_bounds__(128)
void pack_weights(const float* __restrict__ w, const float* __restrict__ g,
                  const float* __restrict__ b, const float* __restrict__ m,
                  const float* __restrict__ v, __hip_bfloat16* __restrict__ Wp2,
                  float* __restrict__ shift)
{
    int o = blockIdx.x;
    int c = threadIdx.x;
    float scale = g[o] * rsqrtf(v[o] + 1e-5f);
    if (c == 0) shift[o] = b[o] - m[o] * scale;
    const float* ws = w + ((size_t)o * C + c) * 9;
    int ks = c >> 4, hi = (c >> 3) & 1, j = c & 7;
    #pragma unroll
    for (int tap = 0; tap < 9; ++tap) {
        size_t idx = ((((size_t)tap * 8 + ks) * 2 + hi) * 128 + o) * 8 + j;
        Wp2[idx] = __float2bfloat16(ws[tap] * scale);
    }
}

// ---------------------------------------------------------------------------
// NCHW fp32 -> padded NHWC bf16 (interior only; halo zeroed separately).
// ---------------------------------------------------------------------------
__global__ __launch_bounds__(256)
void transform_x(const float* __restrict__ x, __hip_bfloat16* __restrict__ Xp)
{
    __shared__ float t[C * 57];
    int bid = blockIdx.x;
    int n = bid / H, h = bid % H;
    int tid = threadIdx.x;

    #pragma unroll
    for (int i = 0; i < 7; ++i) {
        int idx4 = i * 256 + tid;
        int c  = idx4 / 14;
        int wq = (idx4 % 14) * 4;
        const float* p = x + ((size_t)(n * C + c)) * (H * W) + h * W + wq;
        float4 vv = *(const float4*)p;
        t[c * 57 + wq + 0] = vv.x;
        t[c * 57 + wq + 1] = vv.y;
        t[c * 57 + wq + 2] = vv.z;
        t[c * 57 + wq + 3] = vv.w;
    }
    __syncthreads();
    #pragma unroll
    for (int i = 0; i < 28; ++i) {
        int idx = i * 256 + tid;
        int c = idx & 127, w = idx >> 7;
        float vv = t[c * 57 + w];
        Xp[(((size_t)n * HP + (h + 1)) * HP + (w + 1)) * C + c] = __float2bfloat16(vv);
    }
}

// ---------------------------------------------------------------------------
// Zero only the halo of a padded NHWC buffer.
// ---------------------------------------------------------------------------
__global__ __launch_bounds__(256)
void zero_halo(__hip_bfloat16* __restrict__ buf)
{
    int idx = blockIdx.x * 256 + threadIdx.x;
    int n = idx / (228 * 16);
    int rem = idx % (228 * 16);
    int p = rem >> 4, l = rem & 15;
    int y, xq;
    if (p < 58)       { y = 0;  xq = p; }
    else if (p < 116) { y = 57; xq = p - 58; }
    else { int q = p - 116; y = 1 + (q >> 1); xq = (q & 1) * 57; }
    short8* dst = (short8*)(buf + (((size_t)n * HP + y) * HP + xq) * C + l * 8);
    *dst = short8{0,0,0,0,0,0,0,0};
}

// ---------------------------------------------------------------------------
// Implicit-GEMM 3x3 conv.  Block = 256 thr (4 waves), 2 output rows x O=128.
// Wave (wm,oh): row h0+wm, o in [oh*64,+64), m in [0,64): acc[2][2] f32x16.
// X: 3-slot LDS ring (slot stride 15360 B), XOR swizzle ((row&15)<<4) via
//    pre-swizzled gload_lds source.
// W: cooperative LDS double-buffer, ONE 16 KB half-tap B-tile per K-step,
//    staged via gload_lds with XOR swizzle byte^=(((byte>>7)&3)<<5).
//    Single barrier per K-step: { sync; STAGE(ht+1 -> other buf); COMPUTE(ht) }
// ROUND-6 BUGFIX: X fragment channel offset must use the GLOBAL K-slice
//    ks_g = (ht&1)*4 + ks  (odd half-taps read c in [64,128)), matching the
//    W half-tap being staged.  Round 6 used local ks -> wrong operands.
// WHICH==0: D[m][o] -> relu(D+shift) -> NHWC bf16 padded (Y1)
// WHICH==1: D[o][m] -> relu(D+shift+identity) -> NCHW fp32
// ---------------------------------------------------------------------------
template<int WHICH>
__global__ __launch_bounds__(256, 2)
void conv3x3_kernel(const __hip_bfloat16* __restrict__ Xp,
                    const __hip_bfloat16* __restrict__ Wp2,
                    const float* __restrict__ shift,
                    const float* __restrict__ ident,
                    void* __restrict__ outp)
{
    __shared__ char s_x[3 * XSLOT + 2304];   // slots + read-overhang pad
    __shared__ char s_w[2][16384];           // W double buffer (one half-tap)

    const int tid  = threadIdx.x;
    const int wave = tid >> 6;
    const int lane = tid & 63;
    const int lr5  = lane & 31;
    const int hi   = lane >> 5;
    const int wm   = wave >> 1;      // output row within block
    const int oh   = wave & 1;       // o-half

    const int bid0 = blockIdx.x;
    const int bid  = (bid0 & 7) * 224 + (bid0 >> 3);   // XCD chunk swizzle
    const int n = bid / 28, h0 = (bid % 28) * 2;

    const char* xbase = (const char*)Xp + ((size_t)n * HP + h0) * ROWB;

    // prologue: stage padded rows 0..2 -> slots 0..2 (15 x 1KB each)
    #pragma unroll
    for (int slot = 0; slot < 3; ++slot)
        #pragma unroll
        for (int i = 0; i < 4; ++i) {
            int blk = wave + i * 4;
            if (blk < 15) {
                int d = blk * 1024 + lane * 16;
                int s = d ^ (((d >> 8) & 15) << 4);
                gload16(xbase + (size_t)slot * ROWB + s, s_x + slot * XSLOT + d);
            }
        }
    // stage W half-tap 0 -> s_w[0]
    #pragma unroll
    for (int i = 0; i < 4; ++i) {
        int d = (wave * 4 + i) * 1024 + lane * 16;
        int s = d ^ (((d >> 7) & 3) << 5);
        gload16((const char*)Wp2 + s, s_w[0] + d);
    }

    // B-fragment LDS byte offsets within a 16 KB W buffer (swizzled)
    int wboff[2][4];
    #pragma unroll
    for (int of = 0; of < 2; ++of)
        #pragma unroll
        for (int ks = 0; ks < 4; ++ks) {
            int r = (ks * 2 + hi) * 2048 + (oh * 64 + of * 32 + lr5) * 16;
            wboff[of][ks] = r ^ (((r >> 7) & 3) << 5);
        }

    const int sb0 = ((0 + wm) % 3) * XSLOT;
    const int sb1 = ((1 + wm) % 3) * XSLOT;
    const int sb2 = ((2 + wm) % 3) * XSLOT;

    f32x16 acc[2][2];
    #pragma unroll
    for (int i = 0; i < 2; ++i)
        #pragma unroll
        for (int j = 0; j < 2; ++j)
            acc[i][j] = f32x16{0,0,0,0,0,0,0,0,0,0,0,0,0,0,0,0};

    #pragma unroll
    for (int ht = 0; ht < 18; ++ht) {
        __syncthreads();   // closes reads of the buffer about to be staged
                           // + vmcnt(0) drain of last iteration's stage
        if (ht < 17) {
            const char* wsrc = (const char*)Wp2 + (size_t)(ht + 1) * 16384;
            #pragma unroll
            for (int i = 0; i < 4; ++i) {
                int d = (wave * 4 + i) * 1024 + lane * 16;
                int s = d ^ (((d >> 7) & 3) << 5);
                gload16(wsrc + s, s_w[(ht + 1) & 1] + d);
            }
        }
        if (ht == 6) {
            // prefetch padded row 3 -> slot 0 (slot 0 reads ended at ht=5)
            #pragma unroll
            for (int i = 0; i < 4; ++i) {
                int blk = wave + i * 4;
                if (blk < 15) {
                    int d = blk * 1024 + lane * 16;
                    int s = d ^ (((d >> 8) & 15) << 4);
                    gload16(xbase + (size_t)3 * ROWB + s, s_x + d);
                }
            }
        }
        const int tap = ht >> 1;
        const int kh = tap / 3, kw = tap % 3;
        const int sbase = (kh == 0) ? sb0 : (kh == 1 ? sb1 : sb2);
        const char* wcur = s_w[ht & 1];
        const int rowA = lr5 + kw;
        #pragma unroll
        for (int ks = 0; ks < 4; ++ks) {
            // global K-slice channel byte offset (THE round-6 fix):
            const int cb = ((ht & 1) * 4 + ks) * 32 + hi * 16;
            short8 xa0, xa1, wb0, wb1;
            {
                int off = (rowA * 256 + cb) ^ ((rowA & 15) << 4);
                xa0 = *(const short8*)(s_x + sbase + off);
            }
            {
                int row = rowA + 32;
                int off = (row * 256 + cb) ^ ((row & 15) << 4);
                xa1 = *(const short8*)(s_x + sbase + off);
            }
            wb0 = *(const short8*)(wcur + wboff[0][ks]);
            wb1 = *(const short8*)(wcur + wboff[1][ks]);
            if (WHICH == 0) {           // D[m][o]: acc[mf][of]
                acc[0][0] = mfma32(xa0, wb0, acc[0][0]);
                acc[0][1] = mfma32(xa0, wb1, acc[0][1]);
                acc[1][0] = mfma32(xa1, wb0, acc[1][0]);
                acc[1][1] = mfma32(xa1, wb1, acc[1][1]);
            } else {                    // D[o][m]: acc[of][mf]
                acc[0][0] = mfma32(wb0, xa0, acc[0][0]);
                acc[0][1] = mfma32(wb0, xa1, acc[0][1]);
                acc[1][0] = mfma32(wb1, xa0, acc[1][0]);
                acc[1][1] = mfma32(wb1, xa1, acc[1][1]);
            }
        }
    }

    // C/D layout (32x32): col = lane&31, row = (r&3) + 8*(r>>2) + 4*hi
    if (WHICH == 0) {
        __hip_bfloat16* o1 = (__hip_bfloat16*)outp;
        size_t rowb = ((size_t)n * HP + (h0 + wm + 1)) * HP;
        #pragma unroll
        for (int of = 0; of < 2; ++of) {
            int o = oh * 64 + of * 32 + lr5;
            float sh = shift[o];
            #pragma unroll
            for (int mf = 0; mf < 2; ++mf) {
                #pragma unroll
                for (int r = 0; r < 16; ++r) {
                    int m = mf * 32 + 4 * hi + (r & 3) + 8 * (r >> 2);
                    if (m < W) {
                        float f = acc[mf][of][r] + sh;
                        f = f > 0.f ? f : 0.f;
                        o1[(rowb + m + 1) * C + o] = __float2bfloat16(f);
                    }
                }
            }
        }
    } else {
        float* o2 = (float*)outp;
        int h = h0 + wm;
        #pragma unroll
        for (int mf = 0; mf < 2; ++mf) {
            int m = mf * 32 + lr5;
            if (m < W) {
                #pragma unroll
                for (int of = 0; of < 2; ++of) {
                    #pragma unroll
                    for (int q = 0; q < 4; ++q) {
                        int ob = oh * 64 + of * 32 + 4 * hi + 8 * q;
                        f32x4 sh = *(const f32x4*)(shift + ob);
                        #pragma unroll
                        for (int j = 0; j < 4; ++j) {
                            int o = ob + j;
                            size_t idx = ((size_t)(n * C + o) * H + h) * W + m;
                            float f = acc[of][mf][q * 4 + j] + sh[j] + ident[idx];
                            o2[idx] = f > 0.f ? f : 0.f;
                        }
                    }
                }
            }
        }
    }
}

// ---------------------------------------------------------------------------
extern "C" void kernel_launch(void* const* d_in, const int* in_sizes, int n_in,
                              void* d_out, int out_size, void* d_ws, size_t ws_size,
                              hipStream_t stream)
{
    const float* x  = (const float*)d_in[0];
    const float* w1 = (const float*)d_in[1];
    const float* g1 = (const float*)d_in[2];
    const float* b1 = (const float*)d_in[3];
    const float* m1 = (const float*)d_in[4];
    const float* v1 = (const float*)d_in[5];
    const float* w2 = (const float*)d_in[6];
    const float* g2 = (const float*)d_in[7];
    const float* b2 = (const float*)d_in[8];
    const float* m2 = (const float*)d_in[9];
    const float* v2 = (const float*)d_in[10];
    float* out = (float*)d_out;

    char* ws = (char*)d_ws;
    const size_t PADBUF = (size_t)NN * HP * HP * C * 2;    // 55,107,584 B
    const size_t WBUF   = (size_t)9 * 8 * 2 * 128 * 8 * 2; // 294,912 B
    size_t oX  = 0;
    size_t oY  = oX + PADBUF + 32768;    // slack for staging over-read
    size_t oW1 = oY + PADBUF + 32768;
    size_t oW2 = oW1 + WBUF;
    size_t oS1 = oW2 + WBUF;
    size_t oS2 = oS1 + 512;

    __hip_bfloat16* Xp  = (__hip_bfloat16*)(ws + oX);
    __hip_bfloat16* Y1  = (__hip_bfloat16*)(ws + oY);
    __hip_bfloat16* W1p = (__hip_bfloat16*)(ws + oW1);
    __hip_bfloat16* W2p = (__hip_bfloat16*)(ws + oW2);
    float* s1 = (float*)(ws + oS1);
    float* s2 = (float*)(ws + oS2);

    zero_halo<<<912, 256, 0, stream>>>(Xp);
    zero_halo<<<912, 256, 0, stream>>>(Y1);

    pack_weights<<<128, 128, 0, stream>>>(w1, g1, b1, m1, v1, W1p, s1);
    pack_weights<<<128, 128, 0, stream>>>(w2, g2, b2, m2, v2, W2p, s2);
    transform_x<<<NN * H, 256, 0, stream>>>(x, Xp);

    conv3x3_kernel<0><<<NN * 28, 256, 0, stream>>>(Xp, W1p, s1, nullptr, (void*)Y1);
    conv3x3_kernel<1><<<NN * 28, 256, 0, stream>>>(Y1, W2p, s2, x, (void*)out);
}